// Round 7
// baseline (376.381 us; speedup 1.0000x reference)
//
#include <hip/hip_runtime.h>
#include <hip/hip_bf16.h>

#define B64   64
#define DH    512
#define HID   4096
#define VOC   50257
#define NSTEP 4
#define HSZ   (B64*DH)
#define NL0   64
#define NL1   64

typedef __attribute__((ext_vector_type(8)))  short bf16x8;
typedef __attribute__((ext_vector_type(4)))  float f32x4;
typedef __attribute__((ext_vector_type(16))) float f32x16;
typedef __hip_bfloat16 bf16;

__device__ __forceinline__ bf16x8 ldg8(const bf16* p) {
    return *reinterpret_cast<const bf16x8*>(p);
}
__device__ __forceinline__ short f2bf(float x) {
    bf16 h = __float2bfloat16(x);
    return *reinterpret_cast<short*>(&h);
}
__device__ __forceinline__ bf16x8 cvt8(const float* p) {
    f32x4 a = *reinterpret_cast<const f32x4*>(p);
    f32x4 b = *reinterpret_cast<const f32x4*>(p + 4);
    bf16x8 r;
    r[0] = f2bf(a[0]); r[1] = f2bf(a[1]); r[2] = f2bf(a[2]); r[3] = f2bf(a[3]);
    r[4] = f2bf(b[0]); r[5] = f2bf(b[1]); r[6] = f2bf(b[2]); r[7] = f2bf(b[3]);
    return r;
}
__device__ __forceinline__ bf16x8 cvt8r(f32x4 a, f32x4 b) {
    bf16x8 r;
    r[0] = f2bf(a[0]); r[1] = f2bf(a[1]); r[2] = f2bf(a[2]); r[3] = f2bf(a[3]);
    r[4] = f2bf(b[0]); r[5] = f2bf(b[1]); r[6] = f2bf(b[2]); r[7] = f2bf(b[3]);
    return r;
}
__device__ __forceinline__ float sigmf(float x) { return 1.f / (1.f + __expf(-x)); }
__device__ __forceinline__ f32x4 mfma16(bf16x8 a, bf16x8 b, f32x4 c) {
    return __builtin_amdgcn_mfma_f32_16x16x32_bf16(a, b, c, 0, 0, 0);
}
__device__ __forceinline__ f32x16 mfma32(bf16x8 a, bf16x8 b, f32x16 c) {
    return __builtin_amdgcn_mfma_f32_32x32x16_bf16(a, b, c, 0, 0, 0);
}

// ---------------------------------------------------------------------------
// k_prep (unchanged): convert ip_w, hs, 4 GRU weight matrices to bf16; gather
// embed rows for steps 1..3 as bf16.
// ---------------------------------------------------------------------------
__global__ __launch_bounds__(512) void k_prep(
    const float* __restrict__ hs, const float* __restrict__ ipw,
    const float* __restrict__ wi0, const float* __restrict__ wh0,
    const float* __restrict__ wi1, const float* __restrict__ wh1,
    const float* __restrict__ embed, const int* __restrict__ tids,
    bf16* __restrict__ hsb, bf16* __restrict__ ipwb,
    bf16* __restrict__ w0i, bf16* __restrict__ w0h,
    bf16* __restrict__ w1i, bf16* __restrict__ w1h,
    bf16* __restrict__ xemb)
{
    int c = blockIdx.x * 512 + threadIdx.x;
    const float* src; bf16* dst;
    if      (c < 262144) { size_t t = c;           src = ipw + t*8; dst = ipwb + t*8; }
    else if (c < 294912) { size_t t = c - 262144;  src = hs  + t*8; dst = hsb  + t*8; }
    else if (c < 393216) { size_t t = c - 294912;  src = wi0 + t*8; dst = w0i + t*8; }
    else if (c < 491520) { size_t t = c - 393216;  src = wh0 + t*8; dst = w0h + t*8; }
    else if (c < 589824) { size_t t = c - 491520;  src = wi1 + t*8; dst = w1i + t*8; }
    else if (c < 688128) { size_t t = c - 589824;  src = wh1 + t*8; dst = w1h + t*8; }
    else {
        int t = c - 688128;
        int r = t >> 6, j = t & 63;
        int s = r >> 6, b = r & 63;
        int rid = tids[b * NSTEP + s];
        src = embed + (size_t)rid * DH + j * 8;
        dst = xemb  + (size_t)r   * DH + j * 8;
    }
    *reinterpret_cast<bf16x8*>(dst) = cvt8(src);
}

// wait until bar[idx] >= target (relaxed poll, single acquire at exit)
__device__ __forceinline__ void barwait(int* bar, int idx, int target) {
    if (threadIdx.x == 0) {
        while (__hip_atomic_load(&bar[idx], __ATOMIC_RELAXED, __HIP_MEMORY_SCOPE_AGENT) < target)
            __builtin_amdgcn_s_sleep(1);
        (void)__hip_atomic_load(&bar[idx], __ATOMIC_ACQUIRE, __HIP_MEMORY_SCOPE_AGENT);
    }
    __syncthreads();
}
// block-wide: all prior stores done, then release-add
__device__ __forceinline__ void barbump(int* bar, int idx) {
    __syncthreads();
    if (threadIdx.x == 0)
        __hip_atomic_fetch_add(&bar[idx], 1, __ATOMIC_RELEASE, __HIP_MEMORY_SCOPE_AGENT);
}

// ---------------------------------------------------------------------------
// k_rec (unchanged from round 6, verified): 128 blocks x 512 thr,
// layer-split + cooperative h-staging.
// ---------------------------------------------------------------------------
__global__ __launch_bounds__(512) void k_rec(
    const bf16* __restrict__ hsb, const bf16* __restrict__ ipwb, const float* __restrict__ ipb,
    const bf16* __restrict__ w0i, const bf16* __restrict__ w0h,
    const float* __restrict__ bi0, const float* __restrict__ bh0,
    const bf16* __restrict__ w1i, const bf16* __restrict__ w1h,
    const float* __restrict__ bi1, const float* __restrict__ bh1,
    const bf16* __restrict__ xemb,
    bf16* __restrict__ h0b3, bf16* __restrict__ h1b, bf16* __restrict__ hbig,
    int* __restrict__ bar)
{
    __shared__ __align__(16) char smem[131072];
    int tid = threadIdx.x, w = tid >> 6, lane = tid & 63;
    int lr = lane & 15, q = lane >> 4;
    int bid = blockIdx.x;
    bool isL0 = bid < NL0;
    int sub = isL0 ? bid : bid - NL0;
    int dt = sub >> 1, mh = sub & 1;
    int d0 = dt * 16, M0 = mh * 32;
    int mt = w >> 2, kc = w & 3;
    int m0 = M0 + mt * 16, ml = mt * 16;
    int d = d0 + lr;
    int row = m0 + q * 4 + kc;

    if (isL0) {
        float bR0 = bi0[d] + bh0[d], bZ0 = bi0[DH+d] + bh0[DH+d];
        float biN0 = bi0[2*DH+d],    bhN0 = bh0[2*DH+d];
        float* sG = (float*)(smem + 81920);
        f32x4 zero4 = {0.f,0.f,0.f,0.f};
        float h0st;

        {
            const bf16* arow = hsb  + (size_t)(m0 + lr) * HID + kc * 1024 + q * 8;
            const bf16* brow = ipwb + (size_t)(d0 + lr) * HID + kc * 1024 + q * 8;
            f32x4 acc = zero4;
#pragma unroll 8
            for (int k0 = 0; k0 < 1024; k0 += 32)
                acc = mfma16(ldg8(arow + k0), ldg8(brow + k0), acc);
#pragma unroll
            for (int r = 0; r < 4; ++r) sG[(w*4 + r)*64 + lane] = acc[r];
            __syncthreads();
            float S = 0.f;
#pragma unroll
            for (int j = 0; j < 4; ++j) S += sG[((mt*4 + j)*4 + kc)*64 + lane];
            float v = S + ipb[d];
            h0st = v;
            bf16 vb = __float2bfloat16(v);
            h0b3[row * DH + d] = vb;
            h1b[row * DH + d] = vb;
            __syncthreads();
        }

#pragma unroll
        for (int i = 0; i < 6; ++i) {
            int c = tid + 512*i;
            int g = c >> 10, r = (c >> 6) & 15, kg = c & 63;
            const bf16* src = w0h + ((size_t)(g*DH + d0 + r))*DH + kg*8;
            int dst = g*16384 + r*1024 + ((kg*16) ^ ((r & 7) << 4));
            *reinterpret_cast<bf16x8*>(smem + dst) = ldg8(src);
        }

        float giR[NSTEP] = {0,0,0,0}, giZ[NSTEP] = {0,0,0,0}, giN[NSTEP] = {0,0,0,0};
#pragma unroll
        for (int s = 1; s < NSTEP; ++s) {
            const bf16* xr = xemb + (size_t)((s-1)*B64 + m0 + lr)*DH + kc*128 + q*8;
#pragma unroll
            for (int g = 0; g < 3; ++g) {
                const bf16* wr = w0i + (size_t)(g*DH + d0 + lr)*DH + kc*128 + q*8;
                f32x4 a = zero4;
#pragma unroll
                for (int kt = 0; kt < 4; ++kt)
                    a = mfma16(ldg8(xr + kt*32), ldg8(wr + kt*32), a);
#pragma unroll
                for (int r = 0; r < 4; ++r) sG[((g*8 + w)*4 + r)*64 + lane] = a[r];
            }
            __syncthreads();
            float sR = 0, sZ = 0, sN = 0;
#pragma unroll
            for (int j = 0; j < 4; ++j) {
                sR += sG[((0*8 + mt*4 + j)*4 + kc)*64 + lane];
                sZ += sG[((1*8 + mt*4 + j)*4 + kc)*64 + lane];
                sN += sG[((2*8 + mt*4 + j)*4 + kc)*64 + lane];
            }
            giR[s] = sR; giZ[s] = sZ; giN[s] = sN;
            __syncthreads();
        }
        barbump(bar, 0);

        for (int s = 0; s < NSTEP; ++s) {
            barwait(bar, s == 0 ? 0 : s, NL0);
            if (s == 3) barwait(bar, 8 + 0, NL1);
            const bf16* hsrc = h0b3 + (size_t)(s % 3) * HSZ;
#pragma unroll
            for (int i = 0; i < 4; ++i) {
                int c = tid + 512*i;
                int rr = c >> 6, kg = c & 63;
                int dst = 49152 + rr*1024 + ((kg*16) ^ ((rr & 7) << 4));
                *reinterpret_cast<bf16x8*>(smem + dst) =
                    ldg8(hsrc + (size_t)(M0 + rr)*DH + kg*8);
            }
            __syncthreads();
            bf16x8 af[4];
            int arow = ml + lr;
#pragma unroll
            for (int kt = 0; kt < 4; ++kt) {
                int ke = (kc*128 + kt*32 + q*8) * 2;
                af[kt] = *reinterpret_cast<const bf16x8*>(
                    smem + 49152 + arow*1024 + (ke ^ ((arow & 7) << 4)));
            }
            f32x4 ag[3];
#pragma unroll
            for (int g = 0; g < 3; ++g) {
                f32x4 a = zero4;
#pragma unroll
                for (int kt = 0; kt < 4; ++kt) {
                    int ke = (kc*128 + kt*32 + q*8) * 2;
                    bf16x8 b = *reinterpret_cast<const bf16x8*>(
                        smem + g*16384 + lr*1024 + (ke ^ ((lr & 7) << 4)));
                    a = mfma16(af[kt], b, a);
                }
                ag[g] = a;
            }
#pragma unroll
            for (int g = 0; g < 3; ++g)
#pragma unroll
                for (int r = 0; r < 4; ++r)
                    sG[((g*8 + w)*4 + r)*64 + lane] = ag[g][r];
            __syncthreads();
            float G0 = 0, G1 = 0, GN = 0;
#pragma unroll
            for (int j = 0; j < 4; ++j) {
                G0 += sG[((0*8 + mt*4 + j)*4 + kc)*64 + lane];
                G1 += sG[((1*8 + mt*4 + j)*4 + kc)*64 + lane];
                GN += sG[((2*8 + mt*4 + j)*4 + kc)*64 + lane];
            }
            float rg = sigmf(G0 + giR[s] + bR0);
            float zg = sigmf(G1 + giZ[s] + bZ0);
            float ng = tanhf(giN[s] + biN0 + rg * (GN + bhN0));
            h0st = (1.f - zg) * ng + zg * h0st;
            h0b3[(size_t)((s + 1) % 3) * HSZ + row * DH + d] = __float2bfloat16(h0st);
            barbump(bar, 1 + s);
        }
    } else {
        float bR1 = bi1[d] + bh1[d], bZ1 = bi1[DH+d] + bh1[DH+d];
        float biN1 = bi1[2*DH+d],    bhN1 = bh1[2*DH+d];
        float* sG = (float*)(smem + 98304);
        f32x4 zero4 = {0.f,0.f,0.f,0.f};

#pragma unroll
        for (int i = 0; i < 12; ++i) {
            int c = tid + 512*i;
            int mi = c / 3072, rem = c % 3072;
            int g = rem >> 10, r = (rem >> 6) & 15, kg = rem & 63;
            const bf16* base = mi ? w1i : w1h;
            const bf16* src = base + ((size_t)(g*DH + d0 + r))*DH + kg*8;
            int dst = mi*49152 + g*16384 + r*1024 + ((kg*16) ^ ((r & 7) << 4));
            *reinterpret_cast<bf16x8*>(smem + dst) = ldg8(src);
        }
        barwait(bar, 0, NL0);
        float h1st = __bfloat162float(h1b[row * DH + d]);

        int c1 = 0;
        for (int s = 0; s < NSTEP; ++s) {
            barwait(bar, 1 + s, NL0);
            if (s > 0) barwait(bar, 8 + s - 1, NL1);
            const bf16* h0r = h0b3 + (size_t)((s + 1) % 3) * HSZ
                              + (size_t)(m0 + lr)*DH + kc*128 + q*8;
            bf16x8 a0[4];
#pragma unroll
            for (int kt = 0; kt < 4; ++kt) a0[kt] = ldg8(h0r + kt*32);
            const bf16* h1src = h1b + (size_t)c1 * HSZ;
#pragma unroll
            for (int i = 0; i < 4; ++i) {
                int c = tid + 512*i;
                int rr = c >> 6, kg = c & 63;
                int dst = 98304 + rr*1024 + ((kg*16) ^ ((rr & 7) << 4));
                *reinterpret_cast<bf16x8*>(smem + dst) =
                    ldg8(h1src + (size_t)(M0 + rr)*DH + kg*8);
            }
            __syncthreads();
            bf16x8 a1[4];
            int arow = ml + lr;
#pragma unroll
            for (int kt = 0; kt < 4; ++kt) {
                int ke = (kc*128 + kt*32 + q*8) * 2;
                a1[kt] = *reinterpret_cast<const bf16x8*>(
                    smem + 98304 + arow*1024 + (ke ^ ((arow & 7) << 4)));
            }
            f32x4 comb0 = zero4, comb1 = zero4, hN = zero4, iN = zero4;
#pragma unroll
            for (int g = 0; g < 3; ++g) {
                f32x4 aH = zero4, aI = zero4;
#pragma unroll
                for (int kt = 0; kt < 4; ++kt) {
                    int ke = (kc*128 + kt*32 + q*8) * 2;
                    bf16x8 bH = *reinterpret_cast<const bf16x8*>(
                        smem + g*16384 + lr*1024 + (ke ^ ((lr & 7) << 4)));
                    bf16x8 bI = *reinterpret_cast<const bf16x8*>(
                        smem + 49152 + g*16384 + lr*1024 + (ke ^ ((lr & 7) << 4)));
                    aH = mfma16(a1[kt], bH, aH);
                    aI = mfma16(a0[kt], bI, aI);
                }
                if (g == 0) { comb0 = aH; comb0[0] += aI[0]; comb0[1] += aI[1]; comb0[2] += aI[2]; comb0[3] += aI[3]; }
                else if (g == 1) { comb1 = aH; comb1[0] += aI[0]; comb1[1] += aI[1]; comb1[2] += aI[2]; comb1[3] += aI[3]; }
                else { hN = aH; iN = aI; }
            }
            __syncthreads();
#pragma unroll
            for (int r = 0; r < 4; ++r) {
                sG[((0*8 + w)*4 + r)*64 + lane] = comb0[r];
                sG[((1*8 + w)*4 + r)*64 + lane] = comb1[r];
                sG[((2*8 + w)*4 + r)*64 + lane] = hN[r];
                sG[((3*8 + w)*4 + r)*64 + lane] = iN[r];
            }
            __syncthreads();
            float GR = 0, GZ = 0, GhN = 0, GiN = 0;
#pragma unroll
            for (int j = 0; j < 4; ++j) {
                GR  += sG[((0*8 + mt*4 + j)*4 + kc)*64 + lane];
                GZ  += sG[((1*8 + mt*4 + j)*4 + kc)*64 + lane];
                GhN += sG[((2*8 + mt*4 + j)*4 + kc)*64 + lane];
                GiN += sG[((3*8 + mt*4 + j)*4 + kc)*64 + lane];
            }
            float rg = sigmf(GR + bR1);
            float zg = sigmf(GZ + bZ1);
            float ng = tanhf(GiN + biN1 + rg * (GhN + bhN1));
            h1st = (1.f - zg) * ng + zg * h1st;
            bf16 hvb = __float2bfloat16(h1st);
            h1b[(size_t)(c1 ^ 1) * HSZ + row * DH + d] = hvb;
            hbig[(size_t)(row * NSTEP + s) * DH + d] = hvb;
            c1 ^= 1;
            barbump(bar, 8 + s);
        }
    }
}

// ---------------------------------------------------------------------------
// k_logits v7: out(256x50257) = Hbig(256x512 bf16) @ out_w(50257x512 f32)^T
// 786 blocks x 512 thr (8 waves). Block owns 64 n-rows of out_w.
// B (out_w): cooperatively staged per 64-K chunk -> bf16 LDS, DOUBLE-BUFFERED
//   with async split (issue next chunk's coalesced f32 loads BEFORE this
//   chunk's MFMAs; cvt+ds_write after). Conflict-free layout sB[kg][row^kg].
// A (hbig): 256KB, L2-resident -> direct ldg8, 8 hoisted loads/wave/chunk.
// Wave = (n-group w&1: 32 cols) x (m-quarter w>>1: 64 rows); acc 2x16=32 VGPR.
// One __syncthreads per chunk.
// ---------------------------------------------------------------------------
__global__ __launch_bounds__(512, 4) void k_logits(
    const bf16* __restrict__ hbig, const float* __restrict__ outw, float* __restrict__ out)
{
    __shared__ __align__(16) char sB[2][8192];
    int t = threadIdx.x, w = t >> 6, lane = t & 63;
    int l32 = lane & 31, e = lane >> 5;
    int ng = w & 1, mq = w >> 1;
    int n0 = blockIdx.x * 64;
    int n = n0 + ng * 32 + l32;

    // staging role: row = t>>3 (0..63), kg = t&7; coalesced 32B f32 per thread
    int srow = t >> 3, skg = t & 7;
    int srow_c = n0 + srow; if (srow_c > VOC - 1) srow_c = VOC - 1;
    const float* gsrc = outw + (size_t)srow_c * DH + skg * 8;
    int soff = skg * 1024 + ((srow ^ skg) << 4);

    f32x16 acc[2];
#pragma unroll
    for (int i = 0; i < 2; ++i)
#pragma unroll
        for (int j = 0; j < 16; ++j) acc[i][j] = 0.f;

    // prologue: stage chunk 0
    {
        f32x4 ga = *reinterpret_cast<const f32x4*>(gsrc);
        f32x4 gb = *reinterpret_cast<const f32x4*>(gsrc + 4);
        *reinterpret_cast<bf16x8*>(&sB[0][soff]) = cvt8r(ga, gb);
    }
    __syncthreads();

    int cur = 0;
    const bf16* arowbase = hbig + (size_t)(mq * 64 + l32) * DH + e * 8;
    for (int k0 = 0; k0 < DH; k0 += 64) {
        bool more = (k0 + 64 < DH);
        f32x4 ga, gb;
        if (more) {   // issue next-chunk loads early (latency hides under MFMA)
            ga = *reinterpret_cast<const f32x4*>(gsrc + k0 + 64);
            gb = *reinterpret_cast<const f32x4*>(gsrc + k0 + 64 + 4);
        }
        // A prefetch: 8 independent ldg8 from L2-resident hbig
        bf16x8 areg[2][4];
#pragma unroll
        for (int mt = 0; mt < 2; ++mt)
#pragma unroll
            for (int kk = 0; kk < 4; ++kk)
                areg[mt][kk] = ldg8(arowbase + (size_t)mt * 32 * DH + k0 + kk * 16);
        // MFMA from sB[cur]
#pragma unroll
        for (int kk = 0; kk < 4; ++kk) {
            int kg = kk * 2 + e;
            int rr = ng * 32 + l32;
            bf16x8 bfrag = *reinterpret_cast<const bf16x8*>(
                &sB[cur][kg * 1024 + ((rr ^ kg) << 4)]);
            acc[0] = mfma32(areg[0][kk], bfrag, acc[0]);
            acc[1] = mfma32(areg[1][kk], bfrag, acc[1]);
        }
        if (more) {
            *reinterpret_cast<bf16x8*>(&sB[cur ^ 1][soff]) = cvt8r(ga, gb);
            __syncthreads();
            cur ^= 1;
        }
    }
    if (n < VOC) {
#pragma unroll
        for (int mt = 0; mt < 2; ++mt)
#pragma unroll
            for (int reg = 0; reg < 16; ++reg) {
                int m = mq * 64 + mt * 32 + (reg & 3) + 8 * (reg >> 2) + 4 * e;
                out[(size_t)m * VOC + n] = acc[mt][reg];
            }
    }
}

// ---------------------------------------------------------------------------
extern "C" void kernel_launch(void* const* d_in, const int* in_sizes, int n_in,
                              void* d_out, int out_size, void* d_ws, size_t ws_size,
                              hipStream_t stream) {
    const float* hs   = (const float*)d_in[0];
    const int*   tids = (const int*)d_in[1];
    const float* ipw  = (const float*)d_in[2];
    const float* ipb  = (const float*)d_in[3];
    const float* wih0 = (const float*)d_in[4];
    const float* whh0 = (const float*)d_in[5];
    const float* bih0 = (const float*)d_in[6];
    const float* bhh0 = (const float*)d_in[7];
    const float* wih1 = (const float*)d_in[8];
    const float* whh1 = (const float*)d_in[9];
    const float* bih1 = (const float*)d_in[10];
    const float* bhh1 = (const float*)d_in[11];
    const float* embed = (const float*)d_in[12];
    const float* outw  = (const float*)d_in[13];
    float* out = (float*)d_out;

    char* ws = (char*)d_ws;
    int*  bar  = (int*) (ws + 0);
    bf16* hsb  = (bf16*)(ws + 1024);
    bf16* ipwb = (bf16*)(ws + 525312);
    bf16* w0i  = (bf16*)(ws + 4719616);
    bf16* w0h  = (bf16*)(ws + 6292480);
    bf16* w1i  = (bf16*)(ws + 7865344);
    bf16* w1h  = (bf16*)(ws + 9438208);
    bf16* xemb = (bf16*)(ws + 11011072);
    bf16* h0b3 = (bf16*)(ws + 11207680);
    bf16* h1b  = (bf16*)(ws + 11404288);
    bf16* hbig = (bf16*)(ws + 11535360);

    hipMemsetAsync(bar, 0, 256, stream);

    k_prep<<<1368, 512, 0, stream>>>(hs, ipw, wih0, whh0, wih1, whh1, embed, tids,
                                     hsb, ipwb, w0i, w0h, w1i, w1h, xemb);

    k_rec<<<NL0 + NL1, 512, 0, stream>>>(hsb, ipwb, ipb,
                                         w0i, w0h, bih0, bhh0,
                                         w1i, w1h, bih1, bhh1,
                                         xemb, h0b3, h1b, hbig, bar);

    k_logits<<<(VOC + 63) / 64, 512, 0, stream>>>(hbig, outw, out);
}

// Round 8
// 333.069 us; speedup vs baseline: 1.1300x; 1.1300x over previous
//
#include <hip/hip_runtime.h>
#include <hip/hip_bf16.h>

#define B64   64
#define DH    512
#define HID   4096
#define VOC   50257
#define NSTEP 4
#define HSZ   (B64*DH)
#define NL0   64
#define NL1   64
#define NCV   128

typedef __attribute__((ext_vector_type(8)))  short bf16x8;
typedef __attribute__((ext_vector_type(4)))  float f32x4;
typedef __attribute__((ext_vector_type(16))) float f32x16;
typedef __hip_bfloat16 bf16;

__device__ __forceinline__ bf16x8 ldg8(const bf16* p) {
    return *reinterpret_cast<const bf16x8*>(p);
}
__device__ __forceinline__ short f2bf(float x) {
    bf16 h = __float2bfloat16(x);
    return *reinterpret_cast<short*>(&h);
}
__device__ __forceinline__ bf16x8 cvt8(const float* p) {
    f32x4 a = *reinterpret_cast<const f32x4*>(p);
    f32x4 b = *reinterpret_cast<const f32x4*>(p + 4);
    bf16x8 r;
    r[0] = f2bf(a[0]); r[1] = f2bf(a[1]); r[2] = f2bf(a[2]); r[3] = f2bf(a[3]);
    r[4] = f2bf(b[0]); r[5] = f2bf(b[1]); r[6] = f2bf(b[2]); r[7] = f2bf(b[3]);
    return r;
}
__device__ __forceinline__ float sigmf(float x) { return 1.f / (1.f + __expf(-x)); }
__device__ __forceinline__ f32x4 mfma16(bf16x8 a, bf16x8 b, f32x4 c) {
    return __builtin_amdgcn_mfma_f32_16x16x32_bf16(a, b, c, 0, 0, 0);
}
__device__ __forceinline__ f32x16 mfma32(bf16x8 a, bf16x8 b, f32x16 c) {
    return __builtin_amdgcn_mfma_f32_32x32x16_bf16(a, b, c, 0, 0, 0);
}

// ---------------------------------------------------------------------------
// k_prep (unchanged)
// ---------------------------------------------------------------------------
__global__ __launch_bounds__(512) void k_prep(
    const float* __restrict__ hs, const float* __restrict__ ipw,
    const float* __restrict__ wi0, const float* __restrict__ wh0,
    const float* __restrict__ wi1, const float* __restrict__ wh1,
    const float* __restrict__ embed, const int* __restrict__ tids,
    bf16* __restrict__ hsb, bf16* __restrict__ ipwb,
    bf16* __restrict__ w0i, bf16* __restrict__ w0h,
    bf16* __restrict__ w1i, bf16* __restrict__ w1h,
    bf16* __restrict__ xemb)
{
    int c = blockIdx.x * 512 + threadIdx.x;
    const float* src; bf16* dst;
    if      (c < 262144) { size_t t = c;           src = ipw + t*8; dst = ipwb + t*8; }
    else if (c < 294912) { size_t t = c - 262144;  src = hs  + t*8; dst = hsb  + t*8; }
    else if (c < 393216) { size_t t = c - 294912;  src = wi0 + t*8; dst = w0i + t*8; }
    else if (c < 491520) { size_t t = c - 393216;  src = wh0 + t*8; dst = w0h + t*8; }
    else if (c < 589824) { size_t t = c - 491520;  src = wi1 + t*8; dst = w1i + t*8; }
    else if (c < 688128) { size_t t = c - 589824;  src = wh1 + t*8; dst = w1h + t*8; }
    else {
        int t = c - 688128;
        int r = t >> 6, j = t & 63;
        int s = r >> 6, b = r & 63;
        int rid = tids[b * NSTEP + s];
        src = embed + (size_t)rid * DH + j * 8;
        dst = xemb  + (size_t)r   * DH + j * 8;
    }
    *reinterpret_cast<bf16x8*>(dst) = cvt8(src);
}

// wait until bar[idx] >= target (relaxed poll, single acquire at exit)
__device__ __forceinline__ void barwait(int* bar, int idx, int target) {
    if (threadIdx.x == 0) {
        while (__hip_atomic_load(&bar[idx], __ATOMIC_RELAXED, __HIP_MEMORY_SCOPE_AGENT) < target)
            __builtin_amdgcn_s_sleep(1);
        (void)__hip_atomic_load(&bar[idx], __ATOMIC_ACQUIRE, __HIP_MEMORY_SCOPE_AGENT);
    }
    __syncthreads();
}
__device__ __forceinline__ void barbump(int* bar, int idx) {
    __syncthreads();
    if (threadIdx.x == 0)
        __hip_atomic_fetch_add(&bar[idx], 1, __ATOMIC_RELEASE, __HIP_MEMORY_SCOPE_AGENT);
}

// ---------------------------------------------------------------------------
// k_rec v8: blocks 0..127 = round-6 recurrence (verified, unchanged).
// Blocks 128..255 (if launched): stream-convert out_w f32 -> bf16 into outwb,
// overlapped with the recurrence on the otherwise-idle CUs. No barrier
// interaction; kernel boundary publishes outwb to k_logits.
// ---------------------------------------------------------------------------
__global__ __launch_bounds__(512) void k_rec(
    const bf16* __restrict__ hsb, const bf16* __restrict__ ipwb, const float* __restrict__ ipb,
    const bf16* __restrict__ w0i, const bf16* __restrict__ w0h,
    const float* __restrict__ bi0, const float* __restrict__ bh0,
    const bf16* __restrict__ w1i, const bf16* __restrict__ w1h,
    const float* __restrict__ bi1, const float* __restrict__ bh1,
    const bf16* __restrict__ xemb,
    bf16* __restrict__ h0b3, bf16* __restrict__ h1b, bf16* __restrict__ hbig,
    int* __restrict__ bar,
    const float* __restrict__ outw_f, bf16* __restrict__ outwb)
{
    __shared__ __align__(16) char smem[131072];
    int tid = threadIdx.x, w = tid >> 6, lane = tid & 63;
    int bid = blockIdx.x;

    if (bid >= NL0 + NL1) {
        // ---------------- out_w f32 -> bf16 converter ----------------
        const size_t total = (size_t)VOC * DH / 8;   // 3,216,448 chunks
        size_t i = (size_t)(bid - NL0 - NL1) * 512 + tid;
        for (; i < total; i += (size_t)NCV * 512)
            *reinterpret_cast<bf16x8*>(outwb + i * 8) = cvt8(outw_f + i * 8);
        return;
    }

    int lr = lane & 15, q = lane >> 4;
    bool isL0 = bid < NL0;
    int sub = isL0 ? bid : bid - NL0;
    int dt = sub >> 1, mh = sub & 1;
    int d0 = dt * 16, M0 = mh * 32;
    int mt = w >> 2, kc = w & 3;
    int m0 = M0 + mt * 16, ml = mt * 16;
    int d = d0 + lr;
    int row = m0 + q * 4 + kc;

    if (isL0) {
        float bR0 = bi0[d] + bh0[d], bZ0 = bi0[DH+d] + bh0[DH+d];
        float biN0 = bi0[2*DH+d],    bhN0 = bh0[2*DH+d];
        float* sG = (float*)(smem + 81920);
        f32x4 zero4 = {0.f,0.f,0.f,0.f};
        float h0st;

        {
            const bf16* arow = hsb  + (size_t)(m0 + lr) * HID + kc * 1024 + q * 8;
            const bf16* brow = ipwb + (size_t)(d0 + lr) * HID + kc * 1024 + q * 8;
            f32x4 acc = zero4;
#pragma unroll 8
            for (int k0 = 0; k0 < 1024; k0 += 32)
                acc = mfma16(ldg8(arow + k0), ldg8(brow + k0), acc);
#pragma unroll
            for (int r = 0; r < 4; ++r) sG[(w*4 + r)*64 + lane] = acc[r];
            __syncthreads();
            float S = 0.f;
#pragma unroll
            for (int j = 0; j < 4; ++j) S += sG[((mt*4 + j)*4 + kc)*64 + lane];
            float v = S + ipb[d];
            h0st = v;
            bf16 vb = __float2bfloat16(v);
            h0b3[row * DH + d] = vb;
            h1b[row * DH + d] = vb;
            __syncthreads();
        }

#pragma unroll
        for (int i = 0; i < 6; ++i) {
            int c = tid + 512*i;
            int g = c >> 10, r = (c >> 6) & 15, kg = c & 63;
            const bf16* src = w0h + ((size_t)(g*DH + d0 + r))*DH + kg*8;
            int dst = g*16384 + r*1024 + ((kg*16) ^ ((r & 7) << 4));
            *reinterpret_cast<bf16x8*>(smem + dst) = ldg8(src);
        }

        float giR[NSTEP] = {0,0,0,0}, giZ[NSTEP] = {0,0,0,0}, giN[NSTEP] = {0,0,0,0};
#pragma unroll
        for (int s = 1; s < NSTEP; ++s) {
            const bf16* xr = xemb + (size_t)((s-1)*B64 + m0 + lr)*DH + kc*128 + q*8;
#pragma unroll
            for (int g = 0; g < 3; ++g) {
                const bf16* wr = w0i + (size_t)(g*DH + d0 + lr)*DH + kc*128 + q*8;
                f32x4 a = zero4;
#pragma unroll
                for (int kt = 0; kt < 4; ++kt)
                    a = mfma16(ldg8(xr + kt*32), ldg8(wr + kt*32), a);
#pragma unroll
                for (int r = 0; r < 4; ++r) sG[((g*8 + w)*4 + r)*64 + lane] = a[r];
            }
            __syncthreads();
            float sR = 0, sZ = 0, sN = 0;
#pragma unroll
            for (int j = 0; j < 4; ++j) {
                sR += sG[((0*8 + mt*4 + j)*4 + kc)*64 + lane];
                sZ += sG[((1*8 + mt*4 + j)*4 + kc)*64 + lane];
                sN += sG[((2*8 + mt*4 + j)*4 + kc)*64 + lane];
            }
            giR[s] = sR; giZ[s] = sZ; giN[s] = sN;
            __syncthreads();
        }
        barbump(bar, 0);

        for (int s = 0; s < NSTEP; ++s) {
            barwait(bar, s == 0 ? 0 : s, NL0);
            if (s == 3) barwait(bar, 8 + 0, NL1);
            const bf16* hsrc = h0b3 + (size_t)(s % 3) * HSZ;
#pragma unroll
            for (int i = 0; i < 4; ++i) {
                int c = tid + 512*i;
                int rr = c >> 6, kg = c & 63;
                int dst = 49152 + rr*1024 + ((kg*16) ^ ((rr & 7) << 4));
                *reinterpret_cast<bf16x8*>(smem + dst) =
                    ldg8(hsrc + (size_t)(M0 + rr)*DH + kg*8);
            }
            __syncthreads();
            bf16x8 af[4];
            int arow = ml + lr;
#pragma unroll
            for (int kt = 0; kt < 4; ++kt) {
                int ke = (kc*128 + kt*32 + q*8) * 2;
                af[kt] = *reinterpret_cast<const bf16x8*>(
                    smem + 49152 + arow*1024 + (ke ^ ((arow & 7) << 4)));
            }
            f32x4 ag[3];
#pragma unroll
            for (int g = 0; g < 3; ++g) {
                f32x4 a = zero4;
#pragma unroll
                for (int kt = 0; kt < 4; ++kt) {
                    int ke = (kc*128 + kt*32 + q*8) * 2;
                    bf16x8 b = *reinterpret_cast<const bf16x8*>(
                        smem + g*16384 + lr*1024 + (ke ^ ((lr & 7) << 4)));
                    a = mfma16(af[kt], b, a);
                }
                ag[g] = a;
            }
#pragma unroll
            for (int g = 0; g < 3; ++g)
#pragma unroll
                for (int r = 0; r < 4; ++r)
                    sG[((g*8 + w)*4 + r)*64 + lane] = ag[g][r];
            __syncthreads();
            float G0 = 0, G1 = 0, GN = 0;
#pragma unroll
            for (int j = 0; j < 4; ++j) {
                G0 += sG[((0*8 + mt*4 + j)*4 + kc)*64 + lane];
                G1 += sG[((1*8 + mt*4 + j)*4 + kc)*64 + lane];
                GN += sG[((2*8 + mt*4 + j)*4 + kc)*64 + lane];
            }
            float rg = sigmf(G0 + giR[s] + bR0);
            float zg = sigmf(G1 + giZ[s] + bZ0);
            float ng = tanhf(giN[s] + biN0 + rg * (GN + bhN0));
            h0st = (1.f - zg) * ng + zg * h0st;
            h0b3[(size_t)((s + 1) % 3) * HSZ + row * DH + d] = __float2bfloat16(h0st);
            barbump(bar, 1 + s);
        }
    } else {
        float bR1 = bi1[d] + bh1[d], bZ1 = bi1[DH+d] + bh1[DH+d];
        float biN1 = bi1[2*DH+d],    bhN1 = bh1[2*DH+d];
        float* sG = (float*)(smem + 98304);
        f32x4 zero4 = {0.f,0.f,0.f,0.f};

#pragma unroll
        for (int i = 0; i < 12; ++i) {
            int c = tid + 512*i;
            int mi = c / 3072, rem = c % 3072;
            int g = rem >> 10, r = (rem >> 6) & 15, kg = rem & 63;
            const bf16* base = mi ? w1i : w1h;
            const bf16* src = base + ((size_t)(g*DH + d0 + r))*DH + kg*8;
            int dst = mi*49152 + g*16384 + r*1024 + ((kg*16) ^ ((r & 7) << 4));
            *reinterpret_cast<bf16x8*>(smem + dst) = ldg8(src);
        }
        barwait(bar, 0, NL0);
        float h1st = __bfloat162float(h1b[row * DH + d]);

        int c1 = 0;
        for (int s = 0; s < NSTEP; ++s) {
            barwait(bar, 1 + s, NL0);
            if (s > 0) barwait(bar, 8 + s - 1, NL1);
            const bf16* h0r = h0b3 + (size_t)((s + 1) % 3) * HSZ
                              + (size_t)(m0 + lr)*DH + kc*128 + q*8;
            bf16x8 a0[4];
#pragma unroll
            for (int kt = 0; kt < 4; ++kt) a0[kt] = ldg8(h0r + kt*32);
            const bf16* h1src = h1b + (size_t)c1 * HSZ;
#pragma unroll
            for (int i = 0; i < 4; ++i) {
                int c = tid + 512*i;
                int rr = c >> 6, kg = c & 63;
                int dst = 98304 + rr*1024 + ((kg*16) ^ ((rr & 7) << 4));
                *reinterpret_cast<bf16x8*>(smem + dst) =
                    ldg8(h1src + (size_t)(M0 + rr)*DH + kg*8);
            }
            __syncthreads();
            bf16x8 a1[4];
            int arow = ml + lr;
#pragma unroll
            for (int kt = 0; kt < 4; ++kt) {
                int ke = (kc*128 + kt*32 + q*8) * 2;
                a1[kt] = *reinterpret_cast<const bf16x8*>(
                    smem + 98304 + arow*1024 + (ke ^ ((arow & 7) << 4)));
            }
            f32x4 comb0 = zero4, comb1 = zero4, hN = zero4, iN = zero4;
#pragma unroll
            for (int g = 0; g < 3; ++g) {
                f32x4 aH = zero4, aI = zero4;
#pragma unroll
                for (int kt = 0; kt < 4; ++kt) {
                    int ke = (kc*128 + kt*32 + q*8) * 2;
                    bf16x8 bH = *reinterpret_cast<const bf16x8*>(
                        smem + g*16384 + lr*1024 + (ke ^ ((lr & 7) << 4)));
                    bf16x8 bI = *reinterpret_cast<const bf16x8*>(
                        smem + 49152 + g*16384 + lr*1024 + (ke ^ ((lr & 7) << 4)));
                    aH = mfma16(a1[kt], bH, aH);
                    aI = mfma16(a0[kt], bI, aI);
                }
                if (g == 0) { comb0 = aH; comb0[0] += aI[0]; comb0[1] += aI[1]; comb0[2] += aI[2]; comb0[3] += aI[3]; }
                else if (g == 1) { comb1 = aH; comb1[0] += aI[0]; comb1[1] += aI[1]; comb1[2] += aI[2]; comb1[3] += aI[3]; }
                else { hN = aH; iN = aI; }
            }
            __syncthreads();
#pragma unroll
            for (int r = 0; r < 4; ++r) {
                sG[((0*8 + w)*4 + r)*64 + lane] = comb0[r];
                sG[((1*8 + w)*4 + r)*64 + lane] = comb1[r];
                sG[((2*8 + w)*4 + r)*64 + lane] = hN[r];
                sG[((3*8 + w)*4 + r)*64 + lane] = iN[r];
            }
            __syncthreads();
            float GR = 0, GZ = 0, GhN = 0, GiN = 0;
#pragma unroll
            for (int j = 0; j < 4; ++j) {
                GR  += sG[((0*8 + mt*4 + j)*4 + kc)*64 + lane];
                GZ  += sG[((1*8 + mt*4 + j)*4 + kc)*64 + lane];
                GhN += sG[((2*8 + mt*4 + j)*4 + kc)*64 + lane];
                GiN += sG[((3*8 + mt*4 + j)*4 + kc)*64 + lane];
            }
            float rg = sigmf(GR + bR1);
            float zg = sigmf(GZ + bZ1);
            float ng = tanhf(GiN + biN1 + rg * (GhN + bhN1));
            h1st = (1.f - zg) * ng + zg * h1st;
            bf16 hvb = __float2bfloat16(h1st);
            h1b[(size_t)(c1 ^ 1) * HSZ + row * DH + d] = hvb;
            hbig[(size_t)(row * NSTEP + s) * DH + d] = hvb;
            c1 ^= 1;
            barbump(bar, 8 + s);
        }
    }
}

// ---------------------------------------------------------------------------
// k_logits_b (v8): v6's verified structure, B operand read as bf16 directly
// (ldg8 = 8 elems / 16B request -> half the requests, half the bytes of v6).
// 4 B-loads hoisted per chunk; A staged in XOR-swizzled LDS as before.
// ---------------------------------------------------------------------------
__global__ __launch_bounds__(256) void k_logits_b(
    const bf16* __restrict__ hbig, const bf16* __restrict__ outwb, float* __restrict__ out)
{
    __shared__ __align__(16) bf16 sA[256 * 64];
    int t = threadIdx.x, w = t >> 6, lane = t & 63;
    int l32 = lane & 31, e = lane >> 5;
    int mh = w >> 1;
    int n = blockIdx.x * 64 + (w & 1) * 32 + l32;
    int nr = n < VOC ? n : VOC - 1;
    const bf16* brow = outwb + (size_t)nr * DH;

    f32x16 acc[4];
#pragma unroll
    for (int i = 0; i < 4; ++i)
#pragma unroll
        for (int j = 0; j < 16; ++j) acc[i][j] = 0.f;

    for (int k0 = 0; k0 < DH; k0 += 64) {
#pragma unroll
        for (int i = 0; i < 8; ++i) {
            int c = i * 256 + t;
            int m = c >> 3, j = c & 7;
            *reinterpret_cast<bf16x8*>(&sA[m * 64 + ((j ^ (m & 7)) << 3)]) =
                ldg8(hbig + (size_t)m * DH + k0 + j * 8);
        }
        __syncthreads();
        bf16x8 bfv[4];
#pragma unroll
        for (int i = 0; i < 4; ++i)
            bfv[i] = ldg8(brow + k0 + i * 16 + e * 8);
#pragma unroll
        for (int i = 0; i < 4; ++i) {
            int g = i * 2 + e;
#pragma unroll
            for (int mt2 = 0; mt2 < 4; ++mt2) {
                int r = (mh * 4 + mt2) * 32 + l32;
                bf16x8 afrag = *reinterpret_cast<const bf16x8*>(
                    &sA[r * 64 + ((g ^ (r & 7)) << 3)]);
                acc[mt2] = mfma32(afrag, bfv[i], acc[mt2]);
            }
        }
        __syncthreads();
    }
    if (n < VOC) {
#pragma unroll
        for (int mt2 = 0; mt2 < 4; ++mt2)
#pragma unroll
            for (int reg = 0; reg < 16; ++reg) {
                int m = (mh * 4 + mt2) * 32 + (reg & 3) + 8 * (reg >> 2) + 4 * e;
                out[(size_t)m * VOC + n] = acc[mt2][reg];
            }
    }
}

// ---------------------------------------------------------------------------
// k_logits_f (fallback = exact round-6 kernel, f32 B via cvt8)
// ---------------------------------------------------------------------------
__global__ __launch_bounds__(256) void k_logits_f(
    const bf16* __restrict__ hbig, const float* __restrict__ outw, float* __restrict__ out)
{
    __shared__ __align__(16) bf16 sA[256 * 64];
    int t = threadIdx.x, w = t >> 6, lane = t & 63;
    int l32 = lane & 31, e = lane >> 5;
    int mh = w >> 1;
    int n = blockIdx.x * 64 + (w & 1) * 32 + l32;
    int nr = n < VOC ? n : VOC - 1;
    const float* brow = outw + (size_t)nr * DH;

    f32x16 acc[4];
#pragma unroll
    for (int i = 0; i < 4; ++i)
#pragma unroll
        for (int j = 0; j < 16; ++j) acc[i][j] = 0.f;

    for (int k0 = 0; k0 < DH; k0 += 64) {
#pragma unroll
        for (int i = 0; i < 8; ++i) {
            int c = i * 256 + t;
            int m = c >> 3, j = c & 7;
            *reinterpret_cast<bf16x8*>(&sA[m * 64 + ((j ^ (m & 7)) << 3)]) =
                ldg8(hbig + (size_t)m * DH + k0 + j * 8);
        }
        __syncthreads();
#pragma unroll
        for (int kk = 0; kk < 64; kk += 16) {
            bf16x8 bfrag = cvt8(brow + k0 + kk + e * 8);
            int g = (kk >> 3) + e;
#pragma unroll
            for (int mt2 = 0; mt2 < 4; ++mt2) {
                int r = (mh * 4 + mt2) * 32 + l32;
                bf16x8 afrag = *reinterpret_cast<const bf16x8*>(
                    &sA[r * 64 + ((g ^ (r & 7)) << 3)]);
                acc[mt2] = mfma32(afrag, bfrag, acc[mt2]);
            }
        }
        __syncthreads();
    }
    if (n < VOC) {
#pragma unroll
        for (int mt2 = 0; mt2 < 4; ++mt2)
#pragma unroll
            for (int reg = 0; reg < 16; ++reg) {
                int m = (mh * 4 + mt2) * 32 + (reg & 3) + 8 * (reg >> 2) + 4 * e;
                out[(size_t)m * VOC + n] = acc[mt2][reg];
            }
    }
}

// ---------------------------------------------------------------------------
extern "C" void kernel_launch(void* const* d_in, const int* in_sizes, int n_in,
                              void* d_out, int out_size, void* d_ws, size_t ws_size,
                              hipStream_t stream) {
    const float* hs   = (const float*)d_in[0];
    const int*   tids = (const int*)d_in[1];
    const float* ipw  = (const float*)d_in[2];
    const float* ipb  = (const float*)d_in[3];
    const float* wih0 = (const float*)d_in[4];
    const float* whh0 = (const float*)d_in[5];
    const float* bih0 = (const float*)d_in[6];
    const float* bhh0 = (const float*)d_in[7];
    const float* wih1 = (const float*)d_in[8];
    const float* whh1 = (const float*)d_in[9];
    const float* bih1 = (const float*)d_in[10];
    const float* bhh1 = (const float*)d_in[11];
    const float* embed = (const float*)d_in[12];
    const float* outw  = (const float*)d_in[13];
    float* out = (float*)d_out;

    char* ws = (char*)d_ws;
    int*  bar  = (int*) (ws + 0);
    bf16* hsb  = (bf16*)(ws + 1024);
    bf16* ipwb = (bf16*)(ws + 525312);
    bf16* w0i  = (bf16*)(ws + 4719616);
    bf16* w0h  = (bf16*)(ws + 6292480);
    bf16* w1i  = (bf16*)(ws + 7865344);
    bf16* w1h  = (bf16*)(ws + 9438208);
    bf16* xemb = (bf16*)(ws + 11011072);
    bf16* h0b3 = (bf16*)(ws + 11207680);
    bf16* h1b  = (bf16*)(ws + 11404288);
    bf16* hbig = (bf16*)(ws + 11535360);
    bf16* outwb = (bf16*)(ws + 11798528);   // 50257x512 bf16 = 51,463,168 B
    size_t need = 11798528 + (size_t)VOC * DH * 2;
    bool bf16B = (ws_size >= need);

    hipMemsetAsync(bar, 0, 256, stream);

    k_prep<<<1368, 512, 0, stream>>>(hs, ipw, wih0, whh0, wih1, whh1, embed, tids,
                                     hsb, ipwb, w0i, w0h, w1i, w1h, xemb);

    int grid_rec = bf16B ? (NL0 + NL1 + NCV) : (NL0 + NL1);
    k_rec<<<grid_rec, 512, 0, stream>>>(hsb, ipwb, ipb,
                                        w0i, w0h, bih0, bhh0,
                                        w1i, w1h, bih1, bhh1,
                                        xemb, h0b3, h1b, hbig, bar,
                                        outw, outwb);

    if (bf16B)
        k_logits_b<<<(VOC + 63) / 64, 256, 0, stream>>>(hbig, outwb, out);
    else
        k_logits_f<<<(VOC + 63) / 64, 256, 0, stream>>>(hbig, outw, out);
}